// Round 10
// baseline (334.000 us; speedup 1.0000x reference)
//
#include <hip/hip_runtime.h>
#include <math.h>

#define V 100000
#define D 128
#define A 64
#define LVLS 3
#define NN 20000
#define KK 16
#define BK 32
#define TM 96        // row tile: As[96*34]+Bs[32*132] = 29,952 B -> 2 blocks/CU (R7-measured)
#define ASTRIDE 34   // 32 + 2 pad -> measured 0 conflicts (R1/R5/R7)
#define BSTW 132     // 128 + 4 pad (merged B tile; R6/R7-measured 0 conflicts)
#define PSTRIDE 128  // projAll row: [0,64)=node-half (W1+b), [64,128)=neighbor-half (W2)

// MERGED projection (R7-passed, 66 us): C[V][128] = Leaf @ Wcomb[128][128], one pass,
// fused Leaf->out copy on the A staging. Byte-identical to R7.
__global__ __launch_bounds__(256, 2)
void projall_kernel(const float* __restrict__ Leaf, const float* __restrict__ Watt,
                    const float* __restrict__ batt, float* __restrict__ projAll,
                    float* __restrict__ outp) {
    __shared__ float As[TM * ASTRIDE];   // 13.1 KB
    __shared__ float Bs[BK * BSTW];      // 16.9 KB
    int t = threadIdx.x;
    int tx = t & 15, ty = t >> 4;
    int r0 = blockIdx.x * TM;

    const float* srcp[3];
    int rg[3];
#pragma unroll
    for (int jj = 0; jj < 3; ++jj) {
        int r = r0 + (t >> 3) + 32 * jj;
        rg[jj] = r;
        int rr = r < V ? r : V - 1;
        srcp[jj] = Leaf + (size_t)rr * D + ((t & 7) << 2);
    }
    int bc = (t & 31) << 2;
    int bk0 = t >> 5;
    const float* bbase = (bc < 64) ? (Watt + bc)
                                   : (Watt + (size_t)128 * A + (bc - 64));

    float4 bv = *(const float4*)(batt + 4 * tx);
    float accA[6][4], accB[6][4];
#pragma unroll
    for (int i = 0; i < 6; ++i) {
        accA[i][0] = bv.x; accA[i][1] = bv.y; accA[i][2] = bv.z; accA[i][3] = bv.w;
        accB[i][0] = 0.f;  accB[i][1] = 0.f;  accB[i][2] = 0.f;  accB[i][3] = 0.f;
    }

    for (int k0 = 0; k0 < D; k0 += BK) {
#pragma unroll
        for (int jj = 0; jj < 3; ++jj) {
            float4 v = *(const float4*)(srcp[jj] + k0);
            *(float4*)&As[((t >> 3) + 32 * jj) * ASTRIDE + ((t & 7) << 2)] = v;
            if (rg[jj] < V)
                *(float4*)(outp + (size_t)rg[jj] * D + k0 + ((t & 7) << 2)) = v;
        }
#pragma unroll
        for (int ss = 0; ss < 4; ++ss)
            *(float4*)&Bs[(bk0 + 8 * ss) * BSTW + bc] =
                *(const float4*)(bbase + (size_t)(k0 + bk0 + 8 * ss) * A);
        __syncthreads();
#pragma unroll
        for (int kc = 0; kc < BK; kc += 4) {
            float4 b0 = *(const float4*)&Bs[(kc + 0) * BSTW + 4 * tx];
            float4 b1 = *(const float4*)&Bs[(kc + 1) * BSTW + 4 * tx];
            float4 b2 = *(const float4*)&Bs[(kc + 2) * BSTW + 4 * tx];
            float4 b3 = *(const float4*)&Bs[(kc + 3) * BSTW + 4 * tx];
            float4 c0 = *(const float4*)&Bs[(kc + 0) * BSTW + 64 + 4 * tx];
            float4 c1 = *(const float4*)&Bs[(kc + 1) * BSTW + 64 + 4 * tx];
            float4 c2 = *(const float4*)&Bs[(kc + 2) * BSTW + 64 + 4 * tx];
            float4 c3 = *(const float4*)&Bs[(kc + 3) * BSTW + 64 + 4 * tx];
#pragma unroll
            for (int i = 0; i < 6; ++i) {
                float4 a = *(const float4*)&As[(6 * ty + i) * ASTRIDE + kc];
                accA[i][0] = fmaf(a.x, b0.x, accA[i][0]);
                accA[i][0] = fmaf(a.y, b1.x, accA[i][0]);
                accA[i][0] = fmaf(a.z, b2.x, accA[i][0]);
                accA[i][0] = fmaf(a.w, b3.x, accA[i][0]);
                accA[i][1] = fmaf(a.x, b0.y, accA[i][1]);
                accA[i][1] = fmaf(a.y, b1.y, accA[i][1]);
                accA[i][1] = fmaf(a.z, b2.y, accA[i][1]);
                accA[i][1] = fmaf(a.w, b3.y, accA[i][1]);
                accA[i][2] = fmaf(a.x, b0.z, accA[i][2]);
                accA[i][2] = fmaf(a.y, b1.z, accA[i][2]);
                accA[i][2] = fmaf(a.z, b2.z, accA[i][2]);
                accA[i][2] = fmaf(a.w, b3.z, accA[i][2]);
                accA[i][3] = fmaf(a.x, b0.w, accA[i][3]);
                accA[i][3] = fmaf(a.y, b1.w, accA[i][3]);
                accA[i][3] = fmaf(a.z, b2.w, accA[i][3]);
                accA[i][3] = fmaf(a.w, b3.w, accA[i][3]);
                accB[i][0] = fmaf(a.x, c0.x, accB[i][0]);
                accB[i][0] = fmaf(a.y, c1.x, accB[i][0]);
                accB[i][0] = fmaf(a.z, c2.x, accB[i][0]);
                accB[i][0] = fmaf(a.w, c3.x, accB[i][0]);
                accB[i][1] = fmaf(a.x, c0.y, accB[i][1]);
                accB[i][1] = fmaf(a.y, c1.y, accB[i][1]);
                accB[i][1] = fmaf(a.z, c2.y, accB[i][1]);
                accB[i][1] = fmaf(a.w, c3.y, accB[i][1]);
                accB[i][2] = fmaf(a.x, c0.z, accB[i][2]);
                accB[i][2] = fmaf(a.y, c1.z, accB[i][2]);
                accB[i][2] = fmaf(a.z, c2.z, accB[i][2]);
                accB[i][2] = fmaf(a.w, c3.z, accB[i][2]);
                accB[i][3] = fmaf(a.x, c0.w, accB[i][3]);
                accB[i][3] = fmaf(a.y, c1.w, accB[i][3]);
                accB[i][3] = fmaf(a.z, c2.w, accB[i][3]);
                accB[i][3] = fmaf(a.w, c3.w, accB[i][3]);
            }
        }
        __syncthreads();
    }

#pragma unroll
    for (int i = 0; i < 6; ++i) {
        int gr = r0 + 6 * ty + i;
        if (gr < V) {
            float4 oA = make_float4(accA[i][0], accA[i][1], accA[i][2], accA[i][3]);
            float4 oB = make_float4(accB[i][0], accB[i][1], accB[i][2], accB[i][3]);
            *(float4*)(projAll + (size_t)gr * PSTRIDE + 4 * tx) = oA;
            *(float4*)(projAll + (size_t)gr * PSTRIDE + 64 + 4 * tx) = oB;
        }
    }
}

// Wave-per-node commit: winner waves scatter tmp row -> out AND compute the
// proj refresh as a shuffle-matvec (lane c owns output col c; row elements
// broadcast via static __shfl; W2 reads coalesced, 32KB -> L1-resident).
// Zero barriers, zero LDS, 5000 blocks (vs old 313 -> chip was half idle).
__global__ __launch_bounds__(256)
void commit2_kernel(const float* __restrict__ tmp, const float* __restrict__ w2,
                    const int* __restrict__ nodes_l, const int* __restrict__ claim,
                    float* __restrict__ outp, float* __restrict__ projAll, int do_proj) {
    int lane = threadIdx.x & 63;
    int n = blockIdx.x * 4 + (threadIdx.x >> 6);
    int li = lane & 31;

    int v = nodes_l[n];
    if (claim[v] != n) return;            // wave-uniform: non-winner waves exit

    // load tmp row: lanes 0..31 hold elements 4li..4li+3 (lanes 32..63 duplicate)
    float4 e = *(const float4*)&tmp[(size_t)n * D + 4 * li];
    if (lane < 32)                        // fused scatter into out (full row)
        *(float4*)&outp[(size_t)v * D + 4 * li] = e;

    if (!do_proj) return;                 // last level: no refresh needed

    // proj[c] = sum_d row[d] * W2[d][c],  c = lane (0..63)
    const float* w2c = w2 + lane;
    float p0 = 0.f, p1 = 0.f, p2 = 0.f, p3 = 0.f;   // 4 chains (break fma latency)
#pragma unroll 8
    for (int s = 0; s < 32; ++s) {
        float bx = __shfl(e.x, s);
        float by = __shfl(e.y, s);
        float bz = __shfl(e.z, s);
        float bw = __shfl(e.w, s);
        p0 = fmaf(bx, w2c[(size_t)(4 * s + 0) * A], p0);
        p1 = fmaf(by, w2c[(size_t)(4 * s + 1) * A], p1);
        p2 = fmaf(bz, w2c[(size_t)(4 * s + 2) * A], p2);
        p3 = fmaf(bw, w2c[(size_t)(4 * s + 3) * A], p3);
    }
    projAll[(size_t)v * PSTRIDE + 64 + lane] = (p0 + p1) + (p2 + p3);
}

// One wave per node (R7-proven form: 4 nodes/block, hoisted PV gathers).
__global__ __launch_bounds__(256)
void attn_kernel(const float* __restrict__ Wc, const float* __restrict__ projAll,
                 const int* __restrict__ nodes_l, const int* __restrict__ neigh,
                 const float* __restrict__ maskp, const float* __restrict__ weightp,
                 const float* __restrict__ v_att, float* __restrict__ tmp) {
    int lane = threadIdx.x & 63;
    int n = blockIdx.x * 4 + (threadIdx.x >> 6);
    int k16 = lane & 15, q = lane >> 4;

    int   vnode = nodes_l[n];
    int   nbk = neigh[n * KK + k16];
    float wv  = weightp[n * KK + k16];
    float mk  = maskp[n * KK + k16];

    const float* npr = projAll + (size_t)vnode * PSTRIDE + q * 16;
    const float* var = v_att + q * 16;
    const float* pr  = projAll + (size_t)nbk * PSTRIDE + 64 + q * 16;

    float part = 0.f;
#pragma unroll
    for (int j = 0; j < 16; j += 4) {
        float4 npv = *(const float4*)(npr + j);
        float4 vav = *(const float4*)(var + j);
        float4 pv  = *(const float4*)(pr + j);
        float x;
        x = npv.x + pv.x; x = fmaxf(x, 0.01f * x); part = fmaf(x, vav.x, part);
        x = npv.y + pv.y; x = fmaxf(x, 0.01f * x); part = fmaf(x, vav.y, part);
        x = npv.z + pv.z; x = fmaxf(x, 0.01f * x); part = fmaf(x, vav.z, part);
        x = npv.w + pv.w; x = fmaxf(x, 0.01f * x); part = fmaf(x, vav.w, part);
    }
    part += __shfl_xor(part, 16);
    part += __shfl_xor(part, 32);
    float pre = part + mk;

    // hoisted PV gathers (independent of att)
    int half = lane >> 5, li = lane & 31;
    float4 e[8];
#pragma unroll
    for (int m = 0; m < 8; ++m) {
        int nb = __shfl(nbk, 2 * m + half);
        e[m] = *(const float4*)&Wc[(size_t)nb * D + 4 * li];
    }

    float mp = pre, mw = wv;
#pragma unroll
    for (int off = 8; off >= 1; off >>= 1) {
        mp = fmaxf(mp, __shfl_xor(mp, off));
        mw = fmaxf(mw, __shfl_xor(mw, off));
    }
    float ep = __expf(pre - mp), ew = __expf(wv - mw);
    float sp = ep, sw = ew;
#pragma unroll
    for (int off = 8; off >= 1; off >>= 1) {
        sp += __shfl_xor(sp, off);
        sw += __shfl_xor(sw, off);
    }
    float att = (ep / sp) * (ew / sw);

    float ax = 0.f, ay = 0.f, az = 0.f, aw = 0.f;
#pragma unroll
    for (int m = 0; m < 8; ++m) {
        float ak = __shfl(att, 2 * m + half);
        ax = fmaf(e[m].x, ak, ax); ay = fmaf(e[m].y, ak, ay);
        az = fmaf(e[m].z, ak, az); aw = fmaf(e[m].w, ak, aw);
    }
    ax += __shfl_xor(ax, 32); ay += __shfl_xor(ay, 32);
    az += __shfl_xor(az, 32); aw += __shfl_xor(aw, 32);
    if (half == 0) {
        float4 o = make_float4(ax, ay, az, aw);
        *(float4*)&tmp[(size_t)n * D + 4 * li] = o;
    }
}

// claims for ALL levels in one pass (depends only on nodes input)
__global__ void amax3_kernel(const int* __restrict__ nodes, int* __restrict__ claims, int total) {
    int i = blockIdx.x * 256 + threadIdx.x;
    if (i < total) {
        int lvl = i / NN, pos = i - lvl * NN;
        atomicMax(&claims[(size_t)lvl * V + nodes[i]], pos);
    }
}

extern "C" void kernel_launch(void* const* d_in, const int* in_sizes, int n_in,
                              void* d_out, int out_size, void* d_ws, size_t ws_size,
                              hipStream_t stream) {
    const float* Leaf    = (const float*)d_in[0];
    const int*   nodes   = (const int*)d_in[1];
    const int*   neigh   = (const int*)d_in[2];
    const float* masks   = (const float*)d_in[3];
    const float* weights = (const float*)d_in[4];
    const float* Watt    = (const float*)d_in[5];
    const float* batt    = (const float*)d_in[6];
    const float* vatt    = (const float*)d_in[7];
    float* out = (float*)d_out;

    char* ws = (char*)d_ws;
    float* projAll = (float*)ws;                                      // V*128
    float* tmp     = (float*)(ws + (size_t)V * PSTRIDE * 4);          // NN*D
    int*   claims  = (int*)(ws + (size_t)(V * PSTRIDE + NN * D) * 4); // LVLS*V

    hipMemsetAsync(claims, 0xFF, (size_t)LVLS * V * sizeof(int), stream);  // -1
    amax3_kernel<<<(LVLS * NN + 255) / 256, 256, 0, stream>>>(nodes, claims, LVLS * NN);
    // one pass over Leaf: out copy + BOTH projection halves for all V rows
    projall_kernel<<<(V + TM - 1) / TM, 256, 0, stream>>>(Leaf, Watt, batt, projAll, out);

    for (int l = 0; l < LVLS; ++l) {
        const int* nodes_l = nodes + l * NN;
        attn_kernel<<<NN / 4, 256, 0, stream>>>(out, projAll, nodes_l,
                                                neigh + (size_t)l * NN * KK,
                                                masks + (size_t)l * NN * KK,
                                                weights + (size_t)l * NN * KK, vatt, tmp);
        commit2_kernel<<<NN / 4, 256, 0, stream>>>(
            tmp, Watt + (size_t)D * A, nodes_l, claims + (size_t)l * V, out, projAll,
            (l + 1 < LVLS) ? 1 : 0);
    }
}

// Round 11
// 300.196 us; speedup vs baseline: 1.1126x; 1.1126x over previous
//
#include <hip/hip_runtime.h>
#include <math.h>

#define V 100000
#define D 128
#define A 64
#define LVLS 3
#define NN 20000
#define KK 16
#define BK 32
#define TM 96        // row tile: As[96*34]+Bs[32*132] = 29,952 B -> 2 blocks/CU (R7-measured)
#define ASTRIDE 34   // 32 + 2 pad -> measured 0 conflicts (R1/R5/R7)
#define BSTW 132     // 128 + 4 pad (merged B tile; R6/R7-measured 0 conflicts)
#define BK2 16
#define AST2 18      // 16 + 2 pad (commit kernel)
#define BST2 68      // 64 + 4 pad
#define PSTRIDE 128  // projAll row: [0,64)=node-half (W1+b), [64,128)=neighbor-half (W2)

// MERGED projection (R7-passed, 66 us): C[V][128] = Leaf @ Wcomb[128][128], one pass,
// fused Leaf->out copy on the A staging. Byte-identical to R7.
__global__ __launch_bounds__(256, 2)
void projall_kernel(const float* __restrict__ Leaf, const float* __restrict__ Watt,
                    const float* __restrict__ batt, float* __restrict__ projAll,
                    float* __restrict__ outp) {
    __shared__ float As[TM * ASTRIDE];   // 13.1 KB
    __shared__ float Bs[BK * BSTW];      // 16.9 KB
    int t = threadIdx.x;
    int tx = t & 15, ty = t >> 4;
    int r0 = blockIdx.x * TM;

    const float* srcp[3];
    int rg[3];
#pragma unroll
    for (int jj = 0; jj < 3; ++jj) {
        int r = r0 + (t >> 3) + 32 * jj;
        rg[jj] = r;
        int rr = r < V ? r : V - 1;
        srcp[jj] = Leaf + (size_t)rr * D + ((t & 7) << 2);
    }
    int bc = (t & 31) << 2;
    int bk0 = t >> 5;
    const float* bbase = (bc < 64) ? (Watt + bc)
                                   : (Watt + (size_t)128 * A + (bc - 64));

    float4 bv = *(const float4*)(batt + 4 * tx);
    float accA[6][4], accB[6][4];
#pragma unroll
    for (int i = 0; i < 6; ++i) {
        accA[i][0] = bv.x; accA[i][1] = bv.y; accA[i][2] = bv.z; accA[i][3] = bv.w;
        accB[i][0] = 0.f;  accB[i][1] = 0.f;  accB[i][2] = 0.f;  accB[i][3] = 0.f;
    }

    for (int k0 = 0; k0 < D; k0 += BK) {
#pragma unroll
        for (int jj = 0; jj < 3; ++jj) {
            float4 v = *(const float4*)(srcp[jj] + k0);
            *(float4*)&As[((t >> 3) + 32 * jj) * ASTRIDE + ((t & 7) << 2)] = v;
            if (rg[jj] < V)
                *(float4*)(outp + (size_t)rg[jj] * D + k0 + ((t & 7) << 2)) = v;
        }
#pragma unroll
        for (int ss = 0; ss < 4; ++ss)
            *(float4*)&Bs[(bk0 + 8 * ss) * BSTW + bc] =
                *(const float4*)(bbase + (size_t)(k0 + bk0 + 8 * ss) * A);
        __syncthreads();
#pragma unroll
        for (int kc = 0; kc < BK; kc += 4) {
            float4 b0 = *(const float4*)&Bs[(kc + 0) * BSTW + 4 * tx];
            float4 b1 = *(const float4*)&Bs[(kc + 1) * BSTW + 4 * tx];
            float4 b2 = *(const float4*)&Bs[(kc + 2) * BSTW + 4 * tx];
            float4 b3 = *(const float4*)&Bs[(kc + 3) * BSTW + 4 * tx];
            float4 c0 = *(const float4*)&Bs[(kc + 0) * BSTW + 64 + 4 * tx];
            float4 c1 = *(const float4*)&Bs[(kc + 1) * BSTW + 64 + 4 * tx];
            float4 c2 = *(const float4*)&Bs[(kc + 2) * BSTW + 64 + 4 * tx];
            float4 c3 = *(const float4*)&Bs[(kc + 3) * BSTW + 64 + 4 * tx];
#pragma unroll
            for (int i = 0; i < 6; ++i) {
                float4 a = *(const float4*)&As[(6 * ty + i) * ASTRIDE + kc];
                accA[i][0] = fmaf(a.x, b0.x, accA[i][0]);
                accA[i][0] = fmaf(a.y, b1.x, accA[i][0]);
                accA[i][0] = fmaf(a.z, b2.x, accA[i][0]);
                accA[i][0] = fmaf(a.w, b3.x, accA[i][0]);
                accA[i][1] = fmaf(a.x, b0.y, accA[i][1]);
                accA[i][1] = fmaf(a.y, b1.y, accA[i][1]);
                accA[i][1] = fmaf(a.z, b2.y, accA[i][1]);
                accA[i][1] = fmaf(a.w, b3.y, accA[i][1]);
                accA[i][2] = fmaf(a.x, b0.z, accA[i][2]);
                accA[i][2] = fmaf(a.y, b1.z, accA[i][2]);
                accA[i][2] = fmaf(a.z, b2.z, accA[i][2]);
                accA[i][2] = fmaf(a.w, b3.z, accA[i][2]);
                accA[i][3] = fmaf(a.x, b0.w, accA[i][3]);
                accA[i][3] = fmaf(a.y, b1.w, accA[i][3]);
                accA[i][3] = fmaf(a.z, b2.w, accA[i][3]);
                accA[i][3] = fmaf(a.w, b3.w, accA[i][3]);
                accB[i][0] = fmaf(a.x, c0.x, accB[i][0]);
                accB[i][0] = fmaf(a.y, c1.x, accB[i][0]);
                accB[i][0] = fmaf(a.z, c2.x, accB[i][0]);
                accB[i][0] = fmaf(a.w, c3.x, accB[i][0]);
                accB[i][1] = fmaf(a.x, c0.y, accB[i][1]);
                accB[i][1] = fmaf(a.y, c1.y, accB[i][1]);
                accB[i][1] = fmaf(a.z, c2.y, accB[i][1]);
                accB[i][1] = fmaf(a.w, c3.y, accB[i][1]);
                accB[i][2] = fmaf(a.x, c0.z, accB[i][2]);
                accB[i][2] = fmaf(a.y, c1.z, accB[i][2]);
                accB[i][2] = fmaf(a.z, c2.z, accB[i][2]);
                accB[i][2] = fmaf(a.w, c3.z, accB[i][2]);
                accB[i][3] = fmaf(a.x, c0.w, accB[i][3]);
                accB[i][3] = fmaf(a.y, c1.w, accB[i][3]);
                accB[i][3] = fmaf(a.z, c2.w, accB[i][3]);
                accB[i][3] = fmaf(a.w, c3.w, accB[i][3]);
            }
        }
        __syncthreads();
    }

#pragma unroll
    for (int i = 0; i < 6; ++i) {
        int gr = r0 + 6 * ty + i;
        if (gr < V) {
            float4 oA = make_float4(accA[i][0], accA[i][1], accA[i][2], accA[i][3]);
            float4 oB = make_float4(accB[i][0], accB[i][1], accB[i][2], accB[i][3]);
            *(float4*)(projAll + (size_t)gr * PSTRIDE + 4 * tx) = oA;
            *(float4*)(projAll + (size_t)gr * PSTRIDE + 64 + 4 * tx) = oB;
        }
    }
}

// Tile commit (R7-proven): fused scatter (winner rows tmp -> out) + bottom-half
// proj refresh with W2 amortized via LDS (R10's wave-per-node version read 32KB
// of W2 per wave -> 576MB/level of L1 traffic -> +11us/level; reverted).
__global__ __launch_bounds__(256, 4)
void commit_kernel(const float* __restrict__ tmp, const float* __restrict__ Wmat,
                   const int* __restrict__ nodes_l, const int* __restrict__ claim,
                   float* __restrict__ outp, float* __restrict__ projAll, int do_proj) {
    __shared__ float As[64 * AST2];   // 4.6 KB
    __shared__ float Bs[BK2 * BST2];  // 4.4 KB
    int t = threadIdx.x;
    int tx = t & 15, ty = t >> 4;
    int r0 = blockIdx.x * 64;

    int ar = t >> 2;
    int ak = (t & 3) << 2;
    int r = r0 + ar;
    int rr = r < NN ? r : NN - 1;
    const float* asrc = tmp + (size_t)rr * D + ak;
    int vrow = nodes_l[rr];
    int win = (r < NN) && (claim[vrow] == rr);   // last-occurrence-wins

    int bk = t >> 4;
    int bc = (t & 15) << 2;

    float acc[4][4];
#pragma unroll
    for (int i = 0; i < 4; ++i) {
        acc[i][0] = 0.f; acc[i][1] = 0.f; acc[i][2] = 0.f; acc[i][3] = 0.f;
    }

    float4 pa = *(const float4*)(asrc);
    float4 pb = make_float4(0.f, 0.f, 0.f, 0.f);
    if (do_proj) pb = *(const float4*)(Wmat + (size_t)bk * A + bc);

    for (int k0 = 0; k0 < D; k0 += BK2) {
        if (k0) __syncthreads();
        *(float4*)&As[ar * AST2 + ak] = pa;
        if (do_proj) *(float4*)&Bs[bk * BST2 + bc] = pb;
        if (win)
            *(float4*)(outp + (size_t)vrow * D + k0 + ak) = pa;
        __syncthreads();
        int kn = k0 + BK2;
        if (kn < D) {
            pa = *(const float4*)(asrc + kn);
            if (do_proj) pb = *(const float4*)(Wmat + (size_t)(kn + bk) * A + bc);
        }
        if (do_proj) {
#pragma unroll
            for (int kc = 0; kc < BK2; kc += 4) {
                float4 b0 = *(const float4*)&Bs[(kc + 0) * BST2 + 4 * tx];
                float4 b1 = *(const float4*)&Bs[(kc + 1) * BST2 + 4 * tx];
                float4 b2 = *(const float4*)&Bs[(kc + 2) * BST2 + 4 * tx];
                float4 b3 = *(const float4*)&Bs[(kc + 3) * BST2 + 4 * tx];
#pragma unroll
                for (int i = 0; i < 4; ++i) {
                    float4 a = *(const float4*)&As[(4 * ty + i) * AST2 + kc];
                    acc[i][0] = fmaf(a.x, b0.x, acc[i][0]);
                    acc[i][0] = fmaf(a.y, b1.x, acc[i][0]);
                    acc[i][0] = fmaf(a.z, b2.x, acc[i][0]);
                    acc[i][0] = fmaf(a.w, b3.x, acc[i][0]);
                    acc[i][1] = fmaf(a.x, b0.y, acc[i][1]);
                    acc[i][1] = fmaf(a.y, b1.y, acc[i][1]);
                    acc[i][1] = fmaf(a.z, b2.y, acc[i][1]);
                    acc[i][1] = fmaf(a.w, b3.y, acc[i][1]);
                    acc[i][2] = fmaf(a.x, b0.z, acc[i][2]);
                    acc[i][2] = fmaf(a.y, b1.z, acc[i][2]);
                    acc[i][2] = fmaf(a.z, b2.z, acc[i][2]);
                    acc[i][2] = fmaf(a.w, b3.z, acc[i][2]);
                    acc[i][3] = fmaf(a.x, b0.w, acc[i][3]);
                    acc[i][3] = fmaf(a.y, b1.w, acc[i][3]);
                    acc[i][3] = fmaf(a.z, b2.w, acc[i][3]);
                    acc[i][3] = fmaf(a.w, b3.w, acc[i][3]);
                }
            }
        }
    }

    if (do_proj) {
#pragma unroll
        for (int i = 0; i < 4; ++i) {
            int gr = r0 + 4 * ty + i;
            if (gr < NN) {
                int v = nodes_l[gr];
                if (claim[v] == gr) {
                    float4 o = make_float4(acc[i][0], acc[i][1], acc[i][2], acc[i][3]);
                    *(float4*)(projAll + (size_t)v * PSTRIDE + 64 + 4 * tx) = o;
                }
            }
        }
    }
}

// One wave per node, R2-proven math (in-loop PV loads, no e[8] hoist).
// __launch_bounds__(256, 8): force <=64 VGPR -> 8 waves/SIMD (vs ~4 hoisted).
// A/B test: attn is latency-bound on L2/L3 gathers; doubling resident waves
// should cut its time if occupancy was the limiter.
__global__ __launch_bounds__(256, 8)
void attn_kernel(const float* __restrict__ Wc, const float* __restrict__ projAll,
                 const int* __restrict__ nodes_l, const int* __restrict__ neigh,
                 const float* __restrict__ maskp, const float* __restrict__ weightp,
                 const float* __restrict__ v_att, float* __restrict__ tmp) {
    int lane = threadIdx.x & 63;
    int n = blockIdx.x * 4 + (threadIdx.x >> 6);
    int k16 = lane & 15, q = lane >> 4;

    int   vnode = nodes_l[n];
    int   nbk = neigh[n * KK + k16];
    float wv  = weightp[n * KK + k16];
    float mk  = maskp[n * KK + k16];

    const float* npr = projAll + (size_t)vnode * PSTRIDE + q * 16;
    const float* var = v_att + q * 16;
    const float* pr  = projAll + (size_t)nbk * PSTRIDE + 64 + q * 16;

    float part = 0.f;
#pragma unroll
    for (int j = 0; j < 16; j += 4) {
        float4 npv = *(const float4*)(npr + j);
        float4 vav = *(const float4*)(var + j);
        float4 pv  = *(const float4*)(pr + j);
        float x;
        x = npv.x + pv.x; x = fmaxf(x, 0.01f * x); part = fmaf(x, vav.x, part);
        x = npv.y + pv.y; x = fmaxf(x, 0.01f * x); part = fmaf(x, vav.y, part);
        x = npv.z + pv.z; x = fmaxf(x, 0.01f * x); part = fmaf(x, vav.z, part);
        x = npv.w + pv.w; x = fmaxf(x, 0.01f * x); part = fmaf(x, vav.w, part);
    }
    part += __shfl_xor(part, 16);
    part += __shfl_xor(part, 32);
    float pre = part + mk;

    float mp = pre, mw = wv;
#pragma unroll
    for (int off = 8; off >= 1; off >>= 1) {
        mp = fmaxf(mp, __shfl_xor(mp, off));
        mw = fmaxf(mw, __shfl_xor(mw, off));
    }
    float ep = __expf(pre - mp), ew = __expf(wv - mw);
    float sp = ep, sw = ew;
#pragma unroll
    for (int off = 8; off >= 1; off >>= 1) {
        sp += __shfl_xor(sp, off);
        sw += __shfl_xor(sw, off);
    }
    float att = (ep / sp) * (ew / sw);

    // PV: 2 rows/iter, float4/lane, loads in-loop (low VGPR), xor-32 at the end.
    int half = lane >> 5, li = lane & 31;
    float ax = 0.f, ay = 0.f, az = 0.f, aw = 0.f;
#pragma unroll
    for (int m = 0; m < 8; ++m) {
        int src = 2 * m + half;
        int nb   = __shfl(nbk, src);
        float ak = __shfl(att, src);
        float4 e = *(const float4*)&Wc[(size_t)nb * D + 4 * li];
        ax = fmaf(e.x, ak, ax); ay = fmaf(e.y, ak, ay);
        az = fmaf(e.z, ak, az); aw = fmaf(e.w, ak, aw);
    }
    ax += __shfl_xor(ax, 32); ay += __shfl_xor(ay, 32);
    az += __shfl_xor(az, 32); aw += __shfl_xor(aw, 32);
    if (half == 0) {
        float4 o = make_float4(ax, ay, az, aw);
        *(float4*)&tmp[(size_t)n * D + 4 * li] = o;
    }
}

// claims for ALL levels in one pass (depends only on nodes input)
__global__ void amax3_kernel(const int* __restrict__ nodes, int* __restrict__ claims, int total) {
    int i = blockIdx.x * 256 + threadIdx.x;
    if (i < total) {
        int lvl = i / NN, pos = i - lvl * NN;
        atomicMax(&claims[(size_t)lvl * V + nodes[i]], pos);
    }
}

extern "C" void kernel_launch(void* const* d_in, const int* in_sizes, int n_in,
                              void* d_out, int out_size, void* d_ws, size_t ws_size,
                              hipStream_t stream) {
    const float* Leaf    = (const float*)d_in[0];
    const int*   nodes   = (const int*)d_in[1];
    const int*   neigh   = (const int*)d_in[2];
    const float* masks   = (const float*)d_in[3];
    const float* weights = (const float*)d_in[4];
    const float* Watt    = (const float*)d_in[5];
    const float* batt    = (const float*)d_in[6];
    const float* vatt    = (const float*)d_in[7];
    float* out = (float*)d_out;

    char* ws = (char*)d_ws;
    float* projAll = (float*)ws;                                      // V*128
    float* tmp     = (float*)(ws + (size_t)V * PSTRIDE * 4);          // NN*D
    int*   claims  = (int*)(ws + (size_t)(V * PSTRIDE + NN * D) * 4); // LVLS*V

    hipMemsetAsync(claims, 0xFF, (size_t)LVLS * V * sizeof(int), stream);  // -1
    amax3_kernel<<<(LVLS * NN + 255) / 256, 256, 0, stream>>>(nodes, claims, LVLS * NN);
    // one pass over Leaf: out copy + BOTH projection halves for all V rows
    projall_kernel<<<(V + TM - 1) / TM, 256, 0, stream>>>(Leaf, Watt, batt, projAll, out);

    for (int l = 0; l < LVLS; ++l) {
        const int* nodes_l = nodes + l * NN;
        attn_kernel<<<NN / 4, 256, 0, stream>>>(out, projAll, nodes_l,
                                                neigh + (size_t)l * NN * KK,
                                                masks + (size_t)l * NN * KK,
                                                weights + (size_t)l * NN * KK, vatt, tmp);
        commit_kernel<<<(NN + 63) / 64, 256, 0, stream>>>(
            tmp, Watt + (size_t)D * A, nodes_l, claims + (size_t)l * V, out, projAll,
            (l + 1 < LVLS) ? 1 : 0);
    }
}